// Round 3
// baseline (334.381 us; speedup 1.0000x reference)
//
#include <hip/hip_runtime.h>
#include <math.h>

#define N_ROWS  32768
#define K_CODES 1024
#define D_DIM   64
#define NSPLIT  4            // code splits of 256 (4 waves x 64 lanes)
#define C_SHIFT 30.0f        // logit shift keeps expf in fp32 range

// ---- ws float-index layout ----
#define WS_HIST   0                  // [1024] histogram (zeroed by vq_main blk 0)
#define WS_ACC_H  1024               // entropy sum (nats)
#define WS_ACC_C  1025               // commitment sq-diff sum
#define WS_G      2048               // 4 exclusive slices x 4096 (64x64 gram)
#define WS_PART   18432              // [4 sp][32768 rows] float4 (S,U,G,K)

// ---- out float-index layout (reference return order, concatenated) ----
#define OUT_Q      0
#define OUT_COMMIT 2097152
#define OUT_ORTHO  2097153
#define OUT_ENT    2097154
#define OUT_PERP   2097155
#define OUT_COV    2097156
#define OUT_IDX    2097157

// 2048 blocks x 256. Block = (row-tile rg, split sp). Lane = CODE: each lane
// holds its code's 64-float row in VGPRs (loaded once); x rows staged in LDS,
// read as wave-uniform broadcast. Per row: 64 FMA dot + softmax + butterfly.
__global__ __launch_bounds__(256) void vq_main(const float* __restrict__ inp,
                                               const float* __restrict__ emb,
                                               float* __restrict__ ws) {
    __shared__ float  xs[64 * 64];      // 16 KB x-row tile
    __shared__ float4 lp[4][64];        // per-wave per-row partials (S,U,G,K)

    const int t    = threadIdx.x;
    const int lane = t & 63;
    const int w    = t >> 6;
    const int rg   = blockIdx.x >> 2;
    const int sp   = blockIdx.x & 3;

    if (blockIdx.x == 0) {              // zero hist+accs for combine (next launch)
        for (int i = t; i < K_CODES; i += 256) ws[WS_HIST + i] = 0.f;
        if (t == 0) { ws[WS_ACC_H] = 0.f; ws[WS_ACC_C] = 0.f; }
    }

    // stage 64 x-rows, coalesced
    {
        const float4* s4 = (const float4*)(inp + (size_t)rg * 64 * D_DIM);
        float4* x4 = (float4*)xs;
#pragma unroll
        for (int i = 0; i < 4; ++i) x4[t + 256 * i] = s4[t + 256 * i];
    }

    // lane's code row -> 64 VGPRs (once per block), plus ||e||^2 + C
    const int code = sp * 256 + w * 64 + lane;
    float4 E[16];
    {
        const float4* e4 = (const float4*)(emb + (size_t)code * D_DIM);
#pragma unroll
        for (int j = 0; j < 16; ++j) E[j] = e4[j];
    }
    float e2 = C_SHIFT;
#pragma unroll
    for (int j = 0; j < 16; ++j)
        e2 += E[j].x * E[j].x + E[j].y * E[j].y + E[j].z * E[j].z + E[j].w * E[j].w;

    __syncthreads();

    for (int r = 0; r < 64; ++r) {
        const float4* xr = (const float4*)(xs + r * D_DIM);   // broadcast reads
        float d0 = 0.f, d1 = 0.f, d2 = 0.f, d3 = 0.f;
#pragma unroll
        for (int j = 0; j < 16; j += 4) {
            float4 xa = xr[j], xb = xr[j + 1], xc = xr[j + 2], xd = xr[j + 3];
            d0 = fmaf(E[j].x,     xa.x, d0); d0 = fmaf(E[j].y,     xa.y, d0);
            d0 = fmaf(E[j].z,     xa.z, d0); d0 = fmaf(E[j].w,     xa.w, d0);
            d1 = fmaf(E[j + 1].x, xb.x, d1); d1 = fmaf(E[j + 1].y, xb.y, d1);
            d1 = fmaf(E[j + 1].z, xb.z, d1); d1 = fmaf(E[j + 1].w, xb.w, d1);
            d2 = fmaf(E[j + 2].x, xc.x, d2); d2 = fmaf(E[j + 2].y, xc.y, d2);
            d2 = fmaf(E[j + 2].z, xc.z, d2); d2 = fmaf(E[j + 2].w, xc.w, d2);
            d3 = fmaf(E[j + 3].x, xd.x, d3); d3 = fmaf(E[j + 3].y, xd.y, d3);
            d3 = fmaf(E[j + 3].z, xd.z, d3); d3 = fmaf(E[j + 3].w, xd.w, d3);
        }
        float dot = (d0 + d1) + (d2 + d3);
        float g = fmaf(2.0f, dot, -e2);         // shifted logit
        float p = __expf(g);
        float S = p, U = p * g, G = g;
#pragma unroll
        for (int off = 32; off; off >>= 1) {    // butterfly over 64 codes
            S += __shfl_xor(S, off);
            U += __shfl_xor(U, off);
            G = fmaxf(G, __shfl_xor(G, off));
        }
        unsigned long long m = __ballot(g == G);   // lowest lane = lowest code
        int kl = __ffsll(m) - 1;
        if (lane == 0)
            lp[w][r] = make_float4(S, U, G, (float)(sp * 256 + w * 64 + kl));
    }
    __syncthreads();

    if (w == 0) {   // merge 4 chunks (ascending code order), write split partial
        float4 a = lp[0][lane], b = lp[1][lane], c = lp[2][lane], d = lp[3][lane];
        float S = (a.x + b.x) + (c.x + d.x);
        float U = (a.y + b.y) + (c.y + d.y);
        float G = a.z; float K = a.w;
        if (b.z > G) { G = b.z; K = b.w; }
        if (c.z > G) { G = c.z; K = c.w; }
        if (d.z > G) { G = d.z; K = d.w; }
        ((float4*)(ws + WS_PART))[(size_t)sp * N_ROWS + rg * 64 + lane] =
            make_float4(S, U, G, K);
    }
}

// 128 blocks x 256; thread = row. Merge split partials + epilogue.
// Blocks 0..3 additionally compute an exclusive 64x64 gram slice (ortho loss).
__global__ __launch_bounds__(256) void vq_combine(const float* __restrict__ inp,
                                                  const float* __restrict__ emb,
                                                  const float* __restrict__ cc,
                                                  float* __restrict__ ws,
                                                  float* __restrict__ out) {
    __shared__ float redH[4], redC[4];
    const int t   = threadIdx.x;
    const int row = blockIdx.x * 256 + t;

    const float4* P = (const float4*)(ws + WS_PART);
    float S = 0.f, U = 0.f, G = -1e30f, K = 0.f;
#pragma unroll
    for (int sp = 0; sp < NSPLIT; ++sp) {       // ascending split order
        float4 v = P[(size_t)sp * N_ROWS + row];
        S += v.x; U += v.y;
        if (v.z > G) { G = v.z; K = v.w; }
    }
    const int I = (int)K;
    float H = logf(S) - U / S;                  // per-row entropy (nats)

    out[OUT_IDX + row] = K;
    atomicAdd(&ws[WS_HIST + I], 1.0f);

    const float4* xr = (const float4*)(inp + (size_t)row * D_DIM);
    const float4* q4 = (const float4*)(emb + (size_t)I * D_DIM);
    float4* oq = (float4*)out + (size_t)row * 16;
    float cs = 0.f;
#pragma unroll
    for (int j = 0; j < 16; ++j) {
        float4 q = q4[j], x = xr[j];
        float dx = q.x - x.x, dy = q.y - x.y, dz = q.z - x.z, dw = q.w - x.w;
        cs += dx * dx + dy * dy + dz * dz + dw * dw;
        float4 o;
        o.x = x.x + dx; o.y = x.y + dy; o.z = x.z + dz; o.w = x.w + dw;
        oq[j] = o;
    }
#pragma unroll
    for (int off = 32; off; off >>= 1) {
        H  += __shfl_down(H, off);
        cs += __shfl_down(cs, off);
    }
    if ((t & 63) == 0) { redH[t >> 6] = H; redC[t >> 6] = cs; }
    __syncthreads();
    if (t == 0) {
        atomicAdd(&ws[WS_ACC_H], redH[0] + redH[1] + redH[2] + redH[3]);
        atomicAdd(&ws[WS_ACC_C], redC[0] + redC[1] + redC[2] + redC[3]);
    }

    if (blockIdx.x < 4) {                       // gram slice over 256 codes
        __shared__ float srows[64][64];
        __shared__ float srn2[64];
        const int a  = t >> 2;
        const int b0 = (t & 3) << 4;
        float acc[16];
#pragma unroll
        for (int i = 0; i < 16; ++i) acc[i] = 0.f;

        for (int kt = 0; kt < 4; ++kt) {
            const int k0 = blockIdx.x * 256 + kt * 64;
            __syncthreads();                    // srows reuse guard
#pragma unroll
            for (int i = 0; i < 4; ++i) {
                const int r  = i * 16 + (t >> 4);
                const int c4 = (t & 15) << 2;
                float4 v = *(const float4*)(emb + (size_t)(k0 + r) * D_DIM + c4);
                *(float4*)(&srows[r][c4]) = v;
                float ss = v.x * v.x + v.y * v.y + v.z * v.z + v.w * v.w;
                ss += __shfl_down(ss, 8, 16);
                ss += __shfl_down(ss, 4, 16);
                ss += __shfl_down(ss, 2, 16);
                ss += __shfl_down(ss, 1, 16);
                if ((t & 15) == 0) {
                    float nrm = fmaxf(sqrtf(ss), 1e-12f);
                    float msk = (cc[k0 + r] >= 1.0f) ? 1.0f : 0.0f;
                    srn2[r] = msk / (nrm * nrm);   // both scales folded into A
                }
            }
            __syncthreads();
#pragma unroll 4
            for (int k = 0; k < 64; ++k) {
                float na = srows[k][a] * srn2[k];
                const float* rb = &srows[k][b0];
#pragma unroll
                for (int i = 0; i < 16; ++i) acc[i] = fmaf(na, rb[i], acc[i]);
            }
        }
#pragma unroll
        for (int i = 0; i < 16; ++i)
            ws[WS_G + blockIdx.x * 4096 + a * 64 + b0 + i] = acc[i];
    }
}

__global__ __launch_bounds__(256) void vq_finalize(const float* __restrict__ cc,
                                                   const float* __restrict__ ws,
                                                   float* __restrict__ out) {
    __shared__ float redP[4], redG[4], redN[4];
    const int t = threadIdx.x;
    float hp = 0.f, gg = 0.f, nu = 0.f;
    for (int k = t; k < K_CODES; k += 256) {
        float p = ws[WS_HIST + k] * (1.0f / (float)N_ROWS);
        hp += p * logf(p + 1e-10f);
        nu += (cc[k] >= 1.0f) ? 1.0f : 0.0f;
    }
    for (int i = t; i < 4096; i += 256) {
        float g = ws[WS_G + i] + ws[WS_G + 4096 + i]
                + ws[WS_G + 8192 + i] + ws[WS_G + 12288 + i];
        gg = fmaf(g, g, gg);
    }
#pragma unroll
    for (int off = 32; off; off >>= 1) {
        hp += __shfl_down(hp, off);
        gg += __shfl_down(gg, off);
        nu += __shfl_down(nu, off);
    }
    if ((t & 63) == 0) { redP[t >> 6] = hp; redG[t >> 6] = gg; redN[t >> 6] = nu; }
    __syncthreads();
    if (t == 0) {
        float hsum = redP[0] + redP[1] + redP[2] + redP[3];
        float gsum = redG[0] + redG[1] + redG[2] + redG[3];
        float nsum = redN[0] + redN[1] + redN[2] + redN[3];
        out[OUT_PERP]   = expf(-hsum);
        out[OUT_ENT]    = ws[WS_ACC_H] * (1.0f / (float)N_ROWS) * 0.1f; // /log2(1024)
        out[OUT_COMMIT] = ws[WS_ACC_C] * (1.0f / ((float)N_ROWS * (float)D_DIM));
        out[OUT_ORTHO]  = gsum / (nsum * nsum) - 1.0f / nsum;
        out[OUT_COV]    = nsum * (1.0f / (float)K_CODES);
    }
}

extern "C" void kernel_launch(void* const* d_in, const int* in_sizes, int n_in,
                              void* d_out, int out_size, void* d_ws, size_t ws_size,
                              hipStream_t stream) {
    const float* inp = (const float*)d_in[0];   // [16,2048,64]
    const float* emb = (const float*)d_in[1];   // [1024,64]
    const float* cc  = (const float*)d_in[2];   // [1024]
    float* out = (float*)d_out;
    float* ws  = (float*)d_ws;

    vq_main<<<(N_ROWS / 64) * NSPLIT, 256, 0, stream>>>(inp, emb, ws);
    vq_combine<<<N_ROWS / 256, 256, 0, stream>>>(inp, emb, cc, ws, out);
    vq_finalize<<<1, 256, 0, stream>>>(cc, ws, out);
}

// Round 4
// 242.647 us; speedup vs baseline: 1.3781x; 1.3781x over previous
//
#include <hip/hip_runtime.h>
#include <math.h>

#define N_ROWS  32768
#define K_CODES 1024
#define D_DIM   64
#define NSPLIT  8            // code splits: 8 chunks of 128
#define CHUNK   128
#define C_SHIFT 30.0f        // logit shift keeps expf in fp32 range

// ---- ws float-index layout ----
#define WS_HIST   0                  // [1024] histogram (zeroed by vq_main blk 0)
#define WS_ACC_H  1024               // entropy sum (nats)
#define WS_ACC_C  1025               // commitment sq-diff sum
#define WS_G      2048               // 4 exclusive slices x 4096 (64x64 gram)
#define WS_PART   18432              // [8 sp][32768 rows] float4 (S,U,G,K)

// ---- out float-index layout (reference return order, concatenated) ----
#define OUT_Q      0
#define OUT_COMMIT 2097152
#define OUT_ORTHO  2097153
#define OUT_ENT    2097154
#define OUT_PERP   2097155
#define OUT_COV    2097156
#define OUT_IDX    2097157

// 1024 blocks x 256. Block = (row-group of 256 rows, split of 128 codes).
// Lane = row: X in VGPRs, S/U/G/idx in registers (NO cross-lane ops in loop).
// E-chunk staged in LDS once, read wave-uniform broadcast (conflict-free).
__global__ __launch_bounds__(256, 4) void vq_main(const float* __restrict__ inp,
                                                  const float* __restrict__ emb,
                                                  float* __restrict__ ws) {
    __shared__ float es[CHUNK * D_DIM];   // 32 KB embedding chunk
    __shared__ float e2s[CHUNK];          // ||e||^2 + C per chunk code

    const int t    = threadIdx.x;
    const int lane = t & 63;
    const int w    = t >> 6;
    const int rg   = blockIdx.x >> 3;     // row group 0..127
    const int sp   = blockIdx.x & 7;      // split 0..7
    const int row  = rg * 256 + w * 64 + lane;

    if (blockIdx.x == 0) {                // zero hist+accs for combine
        for (int i = t; i < K_CODES; i += 256) ws[WS_HIST + i] = 0.f;
        if (t == 0) { ws[WS_ACC_H] = 0.f; ws[WS_ACC_C] = 0.f; }
    }

    // stage 128 e-rows coalesced; keep the 8 float4s for the e2 reduce
    float4 ebuf[8];
    {
        const float4* s4 = (const float4*)(emb + (size_t)sp * CHUNK * D_DIM);
        float4* d4 = (float4*)es;
#pragma unroll
        for (int i = 0; i < 8; ++i) {
            ebuf[i] = s4[t + 256 * i];
            d4[t + 256 * i] = ebuf[i];
        }
    }

    // X row -> 64 VGPRs (global loads overlap the e2 reduce below)
    float4 X[16];
    const float4* xr = (const float4*)(inp + (size_t)row * D_DIM);
#pragma unroll
    for (int j = 0; j < 16; ++j) X[j] = xr[j];

    // e2: 16 consecutive threads hold one code's row (4 float4s each pass)
#pragma unroll
    for (int i = 0; i < 8; ++i) {
        float4 v = ebuf[i];
        float ss = v.x * v.x + v.y * v.y + v.z * v.z + v.w * v.w;
        ss += __shfl_down(ss, 8, 16);
        ss += __shfl_down(ss, 4, 16);
        ss += __shfl_down(ss, 2, 16);
        ss += __shfl_down(ss, 1, 16);
        if ((t & 15) == 0) e2s[16 * i + (t >> 4)] = ss + C_SHIFT;
    }
    __syncthreads();

    float S = 0.f, U = 0.f, G = -1e30f;
    int kb = 0;

    for (int c = 0; c < CHUNK; ++c) {
        const float4* er = (const float4*)(es + c * D_DIM);  // broadcast
        float e2c = e2s[c];
        float d0 = 0.f, d1 = 0.f, d2 = 0.f, d3 = 0.f;
#pragma unroll
        for (int j = 0; j < 16; j += 4) {
            float4 ea = er[j], eb = er[j + 1], ec = er[j + 2], ed = er[j + 3];
            d0 = fmaf(ea.x, X[j].x,     d0); d0 = fmaf(ea.y, X[j].y,     d0);
            d0 = fmaf(ea.z, X[j].z,     d0); d0 = fmaf(ea.w, X[j].w,     d0);
            d1 = fmaf(eb.x, X[j + 1].x, d1); d1 = fmaf(eb.y, X[j + 1].y, d1);
            d1 = fmaf(eb.z, X[j + 1].z, d1); d1 = fmaf(eb.w, X[j + 1].w, d1);
            d2 = fmaf(ec.x, X[j + 2].x, d2); d2 = fmaf(ec.y, X[j + 2].y, d2);
            d2 = fmaf(ec.z, X[j + 2].z, d2); d2 = fmaf(ec.w, X[j + 2].w, d2);
            d3 = fmaf(ed.x, X[j + 3].x, d3); d3 = fmaf(ed.y, X[j + 3].y, d3);
            d3 = fmaf(ed.z, X[j + 3].z, d3); d3 = fmaf(ed.w, X[j + 3].w, d3);
        }
        float dot = (d0 + d1) + (d2 + d3);
        float g = fmaf(2.0f, dot, -e2c);       // shifted logit
        float p = __expf(g);
        S += p;
        U = fmaf(p, g, U);
        if (g > G) { G = g; kb = c; }          // strict > = first-index ties
    }

    // wave owns distinct rows: write split partial directly (no cross-wave merge)
    ((float4*)(ws + WS_PART))[(size_t)sp * N_ROWS + row] =
        make_float4(S, U, G, (float)(sp * CHUNK + kb));
}

// 128 blocks x 256; thread = row. Merge split partials + epilogue.
// Per-block LDS histogram -> few global atomics. Blocks 0..3: gram slice.
__global__ __launch_bounds__(256) void vq_combine(const float* __restrict__ inp,
                                                  const float* __restrict__ emb,
                                                  const float* __restrict__ cc,
                                                  float* __restrict__ ws,
                                                  float* __restrict__ out) {
    __shared__ int   lhist[K_CODES];
    __shared__ float redH[4], redC[4];
    const int t   = threadIdx.x;
    const int row = blockIdx.x * 256 + t;

#pragma unroll
    for (int i = 0; i < 4; ++i) lhist[t + 256 * i] = 0;
    __syncthreads();

    const float4* P = (const float4*)(ws + WS_PART);
    float S = 0.f, U = 0.f, G = -1e30f, K = 0.f;
#pragma unroll
    for (int sp = 0; sp < NSPLIT; ++sp) {      // ascending split order
        float4 v = P[(size_t)sp * N_ROWS + row];
        S += v.x; U += v.y;
        if (v.z > G) { G = v.z; K = v.w; }
    }
    const int I = (int)K;
    float H = logf(S) - U / S;                 // per-row entropy (nats)

    out[OUT_IDX + row] = K;
    atomicAdd(&lhist[I], 1);

    const float4* xr = (const float4*)(inp + (size_t)row * D_DIM);
    const float4* q4 = (const float4*)(emb + (size_t)I * D_DIM);
    float4* oq = (float4*)out + (size_t)row * 16;
    float cs = 0.f;
#pragma unroll
    for (int j = 0; j < 16; ++j) {
        float4 q = q4[j], x = xr[j];
        float dx = q.x - x.x, dy = q.y - x.y, dz = q.z - x.z, dw = q.w - x.w;
        cs += dx * dx + dy * dy + dz * dz + dw * dw;
        float4 o;
        o.x = x.x + dx; o.y = x.y + dy; o.z = x.z + dz; o.w = x.w + dw;
        oq[j] = o;
    }
#pragma unroll
    for (int off = 32; off; off >>= 1) {
        H  += __shfl_down(H, off);
        cs += __shfl_down(cs, off);
    }
    if ((t & 63) == 0) { redH[t >> 6] = H; redC[t >> 6] = cs; }
    __syncthreads();
    if (t == 0) {
        atomicAdd(&ws[WS_ACC_H], redH[0] + redH[1] + redH[2] + redH[3]);
        atomicAdd(&ws[WS_ACC_C], redC[0] + redC[1] + redC[2] + redC[3]);
    }
    // flush block-local histogram (<=1024 atomics per block, spread addresses)
#pragma unroll
    for (int i = 0; i < 4; ++i) {
        int k = t + 256 * i;
        int cnt = lhist[k];
        if (cnt) atomicAdd(&ws[WS_HIST + k], (float)cnt);
    }

    if (blockIdx.x < 4) {                      // exclusive gram slice, 256 codes
        __shared__ float srows[64][64];
        __shared__ float srn2[64];
        const int a  = t >> 2;
        const int b0 = (t & 3) << 4;
        float acc[16];
#pragma unroll
        for (int i = 0; i < 16; ++i) acc[i] = 0.f;

        for (int kt = 0; kt < 4; ++kt) {
            const int k0 = blockIdx.x * 256 + kt * 64;
            __syncthreads();                   // srows reuse guard
#pragma unroll
            for (int i = 0; i < 4; ++i) {
                const int r  = i * 16 + (t >> 4);
                const int c4 = (t & 15) << 2;
                float4 v = *(const float4*)(emb + (size_t)(k0 + r) * D_DIM + c4);
                *(float4*)(&srows[r][c4]) = v;
                float ss = v.x * v.x + v.y * v.y + v.z * v.z + v.w * v.w;
                ss += __shfl_down(ss, 8, 16);
                ss += __shfl_down(ss, 4, 16);
                ss += __shfl_down(ss, 2, 16);
                ss += __shfl_down(ss, 1, 16);
                if ((t & 15) == 0) {
                    float nrm = fmaxf(sqrtf(ss), 1e-12f);
                    float msk = (cc[k0 + r] >= 1.0f) ? 1.0f : 0.0f;
                    srn2[r] = msk / (nrm * nrm);   // both scales folded into A
                }
            }
            __syncthreads();
#pragma unroll 4
            for (int k = 0; k < 64; ++k) {
                float na = srows[k][a] * srn2[k];
                const float* rb = &srows[k][b0];
#pragma unroll
                for (int i = 0; i < 16; ++i) acc[i] = fmaf(na, rb[i], acc[i]);
            }
        }
#pragma unroll
        for (int i = 0; i < 16; ++i)
            ws[WS_G + blockIdx.x * 4096 + a * 64 + b0 + i] = acc[i];
    }
}

__global__ __launch_bounds__(256) void vq_finalize(const float* __restrict__ cc,
                                                   const float* __restrict__ ws,
                                                   float* __restrict__ out) {
    __shared__ float redP[4], redG[4], redN[4];
    const int t = threadIdx.x;
    float hp = 0.f, gg = 0.f, nu = 0.f;
    for (int k = t; k < K_CODES; k += 256) {
        float p = ws[WS_HIST + k] * (1.0f / (float)N_ROWS);
        hp += p * logf(p + 1e-10f);
        nu += (cc[k] >= 1.0f) ? 1.0f : 0.0f;
    }
    for (int i = t; i < 4096; i += 256) {
        float g = ws[WS_G + i] + ws[WS_G + 4096 + i]
                + ws[WS_G + 8192 + i] + ws[WS_G + 12288 + i];
        gg = fmaf(g, g, gg);
    }
#pragma unroll
    for (int off = 32; off; off >>= 1) {
        hp += __shfl_down(hp, off);
        gg += __shfl_down(gg, off);
        nu += __shfl_down(nu, off);
    }
    if ((t & 63) == 0) { redP[t >> 6] = hp; redG[t >> 6] = gg; redN[t >> 6] = nu; }
    __syncthreads();
    if (t == 0) {
        float hsum = redP[0] + redP[1] + redP[2] + redP[3];
        float gsum = redG[0] + redG[1] + redG[2] + redG[3];
        float nsum = redN[0] + redN[1] + redN[2] + redN[3];
        out[OUT_PERP]   = expf(-hsum);
        out[OUT_ENT]    = ws[WS_ACC_H] * (1.0f / (float)N_ROWS) * 0.1f; // /log2(1024)
        out[OUT_COMMIT] = ws[WS_ACC_C] * (1.0f / ((float)N_ROWS * (float)D_DIM));
        out[OUT_ORTHO]  = gsum / (nsum * nsum) - 1.0f / nsum;
        out[OUT_COV]    = nsum * (1.0f / (float)K_CODES);
    }
}

extern "C" void kernel_launch(void* const* d_in, const int* in_sizes, int n_in,
                              void* d_out, int out_size, void* d_ws, size_t ws_size,
                              hipStream_t stream) {
    const float* inp = (const float*)d_in[0];   // [16,2048,64]
    const float* emb = (const float*)d_in[1];   // [1024,64]
    const float* cc  = (const float*)d_in[2];   // [1024]
    float* out = (float*)d_out;
    float* ws  = (float*)d_ws;

    vq_main<<<(N_ROWS / 256) * NSPLIT, 256, 0, stream>>>(inp, emb, ws);
    vq_combine<<<N_ROWS / 256, 256, 0, stream>>>(inp, emb, cc, ws, out);
    vq_finalize<<<1, 256, 0, stream>>>(cc, ws, out);
}

// Round 7
// 241.806 us; speedup vs baseline: 1.3828x; 1.0035x over previous
//
#include <hip/hip_runtime.h>
#include <math.h>

#define N_ROWS  32768
#define K_CODES 1024
#define D_DIM   64
#define NSPLIT  8            // code splits: 8 chunks of 128
#define CHUNK   128
#define C_SHIFT 30.0f        // logit shift keeps expf in fp32 range

// ---- ws float-index layout ----
#define WS_HIST   0                  // [1024] histogram (zeroed by vq_main blk 0)
#define WS_ACC_H  1024               // entropy sum (nats)
#define WS_ACC_C  1025               // commitment sq-diff sum
#define WS_G      2048               // 4 exclusive slices x 4096 (64x64 gram)
#define WS_PART   18432              // [8 sp][32768 rows] float4 (S,U,G,K)

// ---- out float-index layout (reference return order, concatenated) ----
#define OUT_Q      0
#define OUT_COMMIT 2097152
#define OUT_ORTHO  2097153
#define OUT_ENT    2097154
#define OUT_PERP   2097155
#define OUT_COV    2097156
#define OUT_IDX    2097157

// 1024 blocks x 256. Block = (row-group of 256 rows, split of 128 codes).
// Lane = row: X in VGPRs, S/U/G/idx in registers (NO cross-lane ops in loop).
// E-chunk staged in a float4-typed LDS array -> ds_read_b128 broadcast reads.
__global__ __launch_bounds__(256, 4) void vq_main(const float* __restrict__ inp,
                                                  const float* __restrict__ emb,
                                                  float* __restrict__ ws) {
    __shared__ float4 sm4[CHUNK * (D_DIM / 4)];   // 32 KB, native float4 type
    __shared__ float  e2s[CHUNK];                 // ||e||^2 + C per chunk code

    const int t    = threadIdx.x;
    const int lane = t & 63;
    const int w    = t >> 6;
    const int rg   = blockIdx.x >> 3;     // row group 0..127
    const int sp   = blockIdx.x & 7;      // split 0..7
    const int row  = rg * 256 + w * 64 + lane;

    if (blockIdx.x == 0) {                // zero hist+accs for combine
        for (int i = t; i < K_CODES; i += 256) ws[WS_HIST + i] = 0.f;
        if (t == 0) { ws[WS_ACC_H] = 0.f; ws[WS_ACC_C] = 0.f; }
    }

    // stage 128 e-rows coalesced; ebuf dies before X loads (reg pressure)
    {
        float4 ebuf[8];
        const float4* s4 = (const float4*)(emb + (size_t)sp * CHUNK * D_DIM);
#pragma unroll
        for (int i = 0; i < 8; ++i) {
            ebuf[i] = s4[t + 256 * i];
            sm4[t + 256 * i] = ebuf[i];
        }
        // ||e||^2: 16 consecutive threads hold one code's row per pass
#pragma unroll
        for (int i = 0; i < 8; ++i) {
            float4 v = ebuf[i];
            float ss = v.x * v.x + v.y * v.y + v.z * v.z + v.w * v.w;
            ss += __shfl_down(ss, 8, 16);
            ss += __shfl_down(ss, 4, 16);
            ss += __shfl_down(ss, 2, 16);
            ss += __shfl_down(ss, 1, 16);
            if ((t & 15) == 0) e2s[16 * i + (t >> 4)] = ss + C_SHIFT;
        }
    }

    // X row -> 64 VGPRs
    float4 X[16];
    {
        const float4* xr = (const float4*)(inp + (size_t)row * D_DIM);
#pragma unroll
        for (int j = 0; j < 16; ++j) X[j] = xr[j];
    }
    __syncthreads();

    float S = 0.f, U = 0.f, G = -1e30f;
    int kb = 0;

    for (int c = 0; c < CHUNK; ++c) {
        const float4* er = &sm4[c << 4];       // 16x ds_read_b128, imm offsets
        float e2c = e2s[c];
        float d0 = 0.f, d1 = 0.f, d2 = 0.f, d3 = 0.f;
#pragma unroll
        for (int j = 0; j < 16; j += 4) {
            float4 ea = er[j], eb = er[j + 1], ec = er[j + 2], ed = er[j + 3];
            d0 = fmaf(ea.x, X[j].x,     d0); d0 = fmaf(ea.y, X[j].y,     d0);
            d0 = fmaf(ea.z, X[j].z,     d0); d0 = fmaf(ea.w, X[j].w,     d0);
            d1 = fmaf(eb.x, X[j + 1].x, d1); d1 = fmaf(eb.y, X[j + 1].y, d1);
            d1 = fmaf(eb.z, X[j + 1].z, d1); d1 = fmaf(eb.w, X[j + 1].w, d1);
            d2 = fmaf(ec.x, X[j + 2].x, d2); d2 = fmaf(ec.y, X[j + 2].y, d2);
            d2 = fmaf(ec.z, X[j + 2].z, d2); d2 = fmaf(ec.w, X[j + 2].w, d2);
            d3 = fmaf(ed.x, X[j + 3].x, d3); d3 = fmaf(ed.y, X[j + 3].y, d3);
            d3 = fmaf(ed.z, X[j + 3].z, d3); d3 = fmaf(ed.w, X[j + 3].w, d3);
        }
        float dot = (d0 + d1) + (d2 + d3);
        float g = fmaf(2.0f, dot, -e2c);       // shifted logit
        float p = __expf(g);
        S += p;
        U = fmaf(p, g, U);
        if (g > G) { G = g; kb = c; }          // strict > = first-index ties
    }

    // wave owns distinct rows: write split partial directly
    ((float4*)(ws + WS_PART))[(size_t)sp * N_ROWS + row] =
        make_float4(S, U, G, (float)(sp * CHUNK + kb));
}

// 128 blocks x 256; thread = row. Merge split partials + epilogue.
// Per-block LDS histogram -> few global atomics. Blocks 0..3: gram slice.
__global__ __launch_bounds__(256) void vq_combine(const float* __restrict__ inp,
                                                  const float* __restrict__ emb,
                                                  const float* __restrict__ cc,
                                                  float* __restrict__ ws,
                                                  float* __restrict__ out) {
    __shared__ int   lhist[K_CODES];
    __shared__ float redH[4], redC[4];
    const int t   = threadIdx.x;
    const int row = blockIdx.x * 256 + t;

#pragma unroll
    for (int i = 0; i < 4; ++i) lhist[t + 256 * i] = 0;
    __syncthreads();

    const float4* P = (const float4*)(ws + WS_PART);
    float S = 0.f, U = 0.f, G = -1e30f, K = 0.f;
#pragma unroll
    for (int sp = 0; sp < NSPLIT; ++sp) {      // ascending split order
        float4 v = P[(size_t)sp * N_ROWS + row];
        S += v.x; U += v.y;
        if (v.z > G) { G = v.z; K = v.w; }
    }
    const int I = (int)K;
    float H = logf(S) - U / S;                 // per-row entropy (nats)

    out[OUT_IDX + row] = K;
    atomicAdd(&lhist[I], 1);

    const float4* xr = (const float4*)(inp + (size_t)row * D_DIM);
    const float4* q4 = (const float4*)(emb + (size_t)I * D_DIM);
    float4* oq = (float4*)out + (size_t)row * 16;
    float cs = 0.f;
#pragma unroll
    for (int j = 0; j < 16; ++j) {
        float4 q = q4[j], x = xr[j];
        float dx = q.x - x.x, dy = q.y - x.y, dz = q.z - x.z, dw = q.w - x.w;
        cs += dx * dx + dy * dy + dz * dz + dw * dw;
        float4 o;
        o.x = x.x + dx; o.y = x.y + dy; o.z = x.z + dz; o.w = x.w + dw;
        oq[j] = o;
    }
#pragma unroll
    for (int off = 32; off; off >>= 1) {
        H  += __shfl_down(H, off);
        cs += __shfl_down(cs, off);
    }
    if ((t & 63) == 0) { redH[t >> 6] = H; redC[t >> 6] = cs; }
    __syncthreads();
    if (t == 0) {
        atomicAdd(&ws[WS_ACC_H], redH[0] + redH[1] + redH[2] + redH[3]);
        atomicAdd(&ws[WS_ACC_C], redC[0] + redC[1] + redC[2] + redC[3]);
    }
    // flush block-local histogram (<=1024 atomics per block, spread addresses)
#pragma unroll
    for (int i = 0; i < 4; ++i) {
        int k = t + 256 * i;
        int cnt = lhist[k];
        if (cnt) atomicAdd(&ws[WS_HIST + k], (float)cnt);
    }

    if (blockIdx.x < 4) {                      // exclusive gram slice, 256 codes
        __shared__ float srows[64][64];
        __shared__ float srn2[64];
        const int a  = t >> 2;
        const int b0 = (t & 3) << 4;
        float acc[16];
#pragma unroll
        for (int i = 0; i < 16; ++i) acc[i] = 0.f;

        for (int kt = 0; kt < 4; ++kt) {
            const int k0 = blockIdx.x * 256 + kt * 64;
            __syncthreads();                   // srows reuse guard
#pragma unroll
            for (int i = 0; i < 4; ++i) {
                const int r  = i * 16 + (t >> 4);
                const int c4 = (t & 15) << 2;
                float4 v = *(const float4*)(emb + (size_t)(k0 + r) * D_DIM + c4);
                *(float4*)(&srows[r][c4]) = v;
                float ss = v.x * v.x + v.y * v.y + v.z * v.z + v.w * v.w;
                ss += __shfl_down(ss, 8, 16);
                ss += __shfl_down(ss, 4, 16);
                ss += __shfl_down(ss, 2, 16);
                ss += __shfl_down(ss, 1, 16);
                if ((t & 15) == 0) {
                    float nrm = fmaxf(sqrtf(ss), 1e-12f);
                    float msk = (cc[k0 + r] >= 1.0f) ? 1.0f : 0.0f;
                    srn2[r] = msk / (nrm * nrm);   // both scales folded into A
                }
            }
            __syncthreads();
#pragma unroll 4
            for (int k = 0; k < 64; ++k) {
                float na = srows[k][a] * srn2[k];
                const float* rb = &srows[k][b0];
#pragma unroll
                for (int i = 0; i < 16; ++i) acc[i] = fmaf(na, rb[i], acc[i]);
            }
        }
#pragma unroll
        for (int i = 0; i < 16; ++i)
            ws[WS_G + blockIdx.x * 4096 + a * 64 + b0 + i] = acc[i];
    }
}

__global__ __launch_bounds__(256) void vq_finalize(const float* __restrict__ cc,
                                                   const float* __restrict__ ws,
                                                   float* __restrict__ out) {
    __shared__ float redP[4], redG[4], redN[4];
    const int t = threadIdx.x;
    float hp = 0.f, gg = 0.f, nu = 0.f;
    for (int k = t; k < K_CODES; k += 256) {
        float p = ws[WS_HIST + k] * (1.0f / (float)N_ROWS);
        hp += p * logf(p + 1e-10f);
        nu += (cc[k] >= 1.0f) ? 1.0f : 0.0f;
    }
    for (int i = t; i < 4096; i += 256) {
        float g = ws[WS_G + i] + ws[WS_G + 4096 + i]
                + ws[WS_G + 8192 + i] + ws[WS_G + 12288 + i];
        gg = fmaf(g, g, gg);
    }
#pragma unroll
    for (int off = 32; off; off >>= 1) {
        hp += __shfl_down(hp, off);
        gg += __shfl_down(gg, off);
        nu += __shfl_down(nu, off);
    }
    if ((t & 63) == 0) { redP[t >> 6] = hp; redG[t >> 6] = gg; redN[t >> 6] = nu; }
    __syncthreads();
    if (t == 0) {
        float hsum = redP[0] + redP[1] + redP[2] + redP[3];
        float gsum = redG[0] + redG[1] + redG[2] + redG[3];
        float nsum = redN[0] + redN[1] + redN[2] + redN[3];
        out[OUT_PERP]   = expf(-hsum);
        out[OUT_ENT]    = ws[WS_ACC_H] * (1.0f / (float)N_ROWS) * 0.1f; // /log2(1024)
        out[OUT_COMMIT] = ws[WS_ACC_C] * (1.0f / ((float)N_ROWS * (float)D_DIM));
        out[OUT_ORTHO]  = gsum / (nsum * nsum) - 1.0f / nsum;
        out[OUT_COV]    = nsum * (1.0f / (float)K_CODES);
    }
}

extern "C" void kernel_launch(void* const* d_in, const int* in_sizes, int n_in,
                              void* d_out, int out_size, void* d_ws, size_t ws_size,
                              hipStream_t stream) {
    const float* inp = (const float*)d_in[0];   // [16,2048,64]
    const float* emb = (const float*)d_in[1];   // [1024,64]
    const float* cc  = (const float*)d_in[2];   // [1024]
    float* out = (float*)d_out;
    float* ws  = (float*)d_ws;

    vq_main<<<(N_ROWS / 256) * NSPLIT, 256, 0, stream>>>(inp, emb, ws);
    vq_combine<<<N_ROWS / 256, 256, 0, stream>>>(inp, emb, cc, ws, out);
    vq_finalize<<<1, 256, 0, stream>>>(cc, ws, out);
}